// Round 1
// baseline (388.791 us; speedup 1.0000x reference)
//
#include <hip/hip_runtime.h>
#include <cstdint>

typedef unsigned short u16;
typedef __bf16 bf16x8 __attribute__((ext_vector_type(8)));
typedef float f32x4 __attribute__((ext_vector_type(4)));

#define T_SEQ  2048
#define D_DIM  1024
#define H_DIM  512
#define E_NUM  8
#define M_TOK  2048
#define BT_TOK 4096
#define MAXP   3072   // M + E*128 padding worst case, rounded

static __device__ __forceinline__ u16 f2bf(float f) {
    union { float f; uint32_t u; } v; v.f = f;
    uint32_t u = v.u;
    return (u16)((u + 0x7FFFu + ((u >> 16) & 1u)) >> 16);  // RNE
}
static __device__ __forceinline__ uint32_t pack2(float a, float b) {
    return (uint32_t)f2bf(a) | ((uint32_t)f2bf(b) << 16);
}

// ---------------- x fp32 -> bf16 (once; reused by G1 + E1 gather) ----------------
__global__ __launch_bounds__(256) void cvt_x_kernel(const float* __restrict__ x,
                                                    u16* __restrict__ xb) {
    int i = blockIdx.x * 256 + threadIdx.x;   // one float4 per thread, exact cover
    float4 v = ((const float4*)x)[i];
    uint2 o;
    o.x = pack2(v.x, v.y);
    o.y = pack2(v.z, v.w);
    ((uint2*)xb)[i] = o;
}

// ---------------- gating: fp32 dots, sigmoid, argmax, 2-way softmax ----------------
__global__ __launch_bounds__(256)
void gating_kernel(const float* __restrict__ x,
                   const int* __restrict__ ib, const int* __restrict__ itx,
                   const float* __restrict__ sgw, const float* __restrict__ sgb,
                   const float* __restrict__ egw, const float* __restrict__ egb,
                   const float* __restrict__ ebias,
                   float* __restrict__ shw, float* __restrict__ expw,
                   int* __restrict__ top1, int* __restrict__ rowidx)
{
    int m = blockIdx.x, tid = threadIdx.x;
    __shared__ float xs[D_DIM];
    __shared__ float sc[9];
    int row = ib[m] * T_SEQ + itx[m];
    if (tid == 0) rowidx[m] = row;
    const float* xr = x + (size_t)row * D_DIM;
    ((float4*)xs)[tid] = ((const float4*)xr)[tid];
    __syncthreads();
    int lane = tid & 63, w = tid >> 6;
    for (int sidx = w; sidx < 9; sidx += 4) {
        const float* wr = (sidx == 0) ? sgw : (egw + (size_t)(sidx - 1) * D_DIM);
        float acc = 0.f;
        for (int i = lane; i < D_DIM; i += 64) acc += xs[i] * wr[i];
        #pragma unroll
        for (int o = 32; o > 0; o >>= 1) acc += __shfl_xor(acc, o);
        if (lane == 0) sc[sidx] = acc;
    }
    __syncthreads();
    if (tid == 0) {
        float ss = 1.f / (1.f + expf(-(sc[0] + sgb[0])));
        float es[E_NUM];
        float best = -1e30f; int bi = 0;
        #pragma unroll
        for (int e = 0; e < E_NUM; ++e) {
            es[e] = 1.f / (1.f + expf(-(sc[1 + e] + egb[e])));
            float t = es[e] + ebias[e];
            if (t > best) { best = t; bi = e; }   // strict > == jnp.argmax first-max
        }
        float ts = es[bi];
        shw[m]  = 1.f / (1.f + expf(ts - ss));    // softmax([ss,ts])[0]
        expw[m] = 1.f / (1.f + expf(ss - ts));    // softmax([ss,ts])[1]
        top1[m] = bi;
    }
}

// ---------------- bucket tokens by expert, 128-aligned bases ----------------
__global__ void bucket_kernel(const int* __restrict__ top1,
                              int* __restrict__ base, int* __restrict__ cnt,
                              int* __restrict__ perm)
{
    __shared__ int lc[E_NUM], lb[E_NUM + 1], cur[E_NUM];
    int tid = threadIdx.x;
    if (tid < E_NUM) { lc[tid] = 0; cur[tid] = 0; }
    __syncthreads();
    for (int m = tid; m < M_TOK; m += 256) atomicAdd(&lc[top1[m]], 1);
    __syncthreads();
    if (tid == 0) {
        int bacc = 0;
        for (int e = 0; e < E_NUM; ++e) { lb[e] = bacc; bacc += (lc[e] + 127) & ~127; }
        lb[E_NUM] = bacc;
    }
    __syncthreads();
    for (int m = tid; m < M_TOK; m += 256) {
        int e = top1[m];
        int pos = lb[e] + atomicAdd(&cur[e], 1);
        perm[pos] = m;
    }
    if (tid <= E_NUM) base[tid] = lb[tid];
    if (tid < E_NUM)  cnt[tid]  = lc[tid];
}

// ---------------- silu-gate + LayerNorm, fp32 in -> bf16 out ----------------
template<bool SEL>
__global__ __launch_bounds__(256)
void ln_kernel(const float* __restrict__ X,
               const float* __restrict__ g, const float* __restrict__ b,
               u16* __restrict__ out,
               const int* __restrict__ base, const int* __restrict__ cnt)
{
    int m = blockIdx.x;
    int tid = threadIdx.x;
    if (SEL) {
        bool valid = false;
        int tot = base[E_NUM];
        if (m < tot) {
            int e = 0;
            while (!(m >= base[e] && m < base[e + 1])) ++e;
            valid = (m - base[e]) < cnt[e];
        }
        if (!valid) {  // zero padding rows so E2's A-tiles are clean
            out[(size_t)m * H_DIM + tid] = 0;
            out[(size_t)m * H_DIM + tid + 256] = 0;
            return;
        }
    }
    const float* row = X + (size_t)m * D_DIM;   // [0:512]=x1, [512:1024]=x2
    float a0 = row[tid],       c0 = row[H_DIM + tid];
    float a1 = row[tid + 256], c1 = row[H_DIM + tid + 256];
    float v0 = (a0 / (1.f + expf(-a0))) * c0;
    float v1 = (a1 / (1.f + expf(-a1))) * c1;
    float s = v0 + v1, s2 = v0 * v0 + v1 * v1;
    #pragma unroll
    for (int o = 32; o > 0; o >>= 1) {
        s  += __shfl_xor(s, o);
        s2 += __shfl_xor(s2, o);
    }
    __shared__ float red[8];
    int w = tid >> 6;
    if ((tid & 63) == 0) { red[w] = s; red[4 + w] = s2; }
    __syncthreads();
    s  = red[0] + red[1] + red[2] + red[3];
    s2 = red[4] + red[5] + red[6] + red[7];
    float mu  = s * (1.f / H_DIM);
    float var = s2 * (1.f / H_DIM) - mu * mu;
    float inv = rsqrtf(var + 1e-5f);
    out[(size_t)m * H_DIM + tid]       = f2bf((v0 - mu) * inv * g[tid] + b[tid]);
    out[(size_t)m * H_DIM + tid + 256] = f2bf((v1 - mu) * inv * g[tid + 256] + b[tid + 256]);
}

// ---------------- MFMA GEMM: C[m][n] = sum_k A[m][k] * W[n][k] (+ epilogue) ----------------
// MODE 0: G1  A=x_bf16, W=sw1|sw2 split 512, store fp32 -> x12 ws (+sb1|sb2)
// MODE 1: G2  A=sh,     W=sw3,              store fp32 -> d_out (+sb3)
// MODE 2: E1  A=x_bf16 gathered via perm/rowidx, W=ew1|ew2[e], store -> h12 (+eb1|eb2[e])
// MODE 3: E2  A=z (bucket rows), W=ew3[e], blend-store d_out[row] = d_out*shw + (acc+eb3[e])*expw
template<int MODE, int KLEN>
__global__ __launch_bounds__(256, 2)
void gemm_kernel(const u16* __restrict__ A, int lda,
                 const float* __restrict__ W0, const float* __restrict__ W1, int nsplit,
                 const float* __restrict__ b0, const float* __restrict__ b1,
                 float* __restrict__ C,
                 const int* __restrict__ base, const int* __restrict__ cnt,
                 const int* __restrict__ perm, const int* __restrict__ rowidx,
                 const float* __restrict__ shw, const float* __restrict__ expw)
{
    const int tid   = threadIdx.x;
    const int bn    = blockIdx.x;
    const int bm    = blockIdx.y;
    const int mbase = bm * 128;

    int pend = 0;
    if (MODE >= 2) {
        const int tot = base[E_NUM];
        if (mbase >= tot) return;          // block-uniform exit before any barrier
        int e = 0;
        while (!(mbase >= base[e] && mbase < base[e + 1])) ++e;
        pend = base[e] + cnt[e];
        const size_t wstride = (size_t)H_DIM * D_DIM;  // 524288 for ew1/ew2/ew3 alike
        W0 += (size_t)e * wstride;
        if (MODE == 2) W1 += (size_t)e * wstride;
        b0 += e * ((MODE == 2) ? H_DIM : D_DIM);
        if (MODE == 2) b1 += e * H_DIM;
    }

    __shared__ u16 As[128 * 72];   // stride 72 (=144B): 2-way max bank aliasing (free)
    __shared__ u16 Bs[128 * 72];

    const int kg = tid & 7;        // k-group of 8 elements
    const int r0 = tid >> 3;       // 0..31

    // row pointers are K-invariant: hoist gather + weight-split out of the K loop
    const u16*   arow[4];
    const float* wrow[4];
    #pragma unroll
    for (int it = 0; it < 4; ++it) {
        int r = r0 + 32 * it;
        int grow;
        if (MODE == 2) {
            int p  = mbase + r;
            int pp = (p < pend) ? p : (pend - 1);   // clamp padding rows to a valid token
            grow = rowidx[perm[pp]];
        } else {
            grow = mbase + r;   // MODE 0/1: dense rows; MODE 3: z bucket rows
        }
        arow[it] = A + (size_t)grow * lda + kg * 8;
        int n = bn * 128 + r;
        wrow[it] = ((n < nsplit) ? (W0 + (size_t)n * KLEN)
                                 : (W1 + (size_t)(n - nsplit) * KLEN)) + kg * 8;
    }

    const int lane = tid & 63;
    const int wid  = tid >> 6;
    const int wm   = wid >> 1, wn = wid & 1;
    const int l16  = lane & 15, quad = lane >> 4;

    f32x4 acc[4][4];
    #pragma unroll
    for (int i = 0; i < 4; ++i)
        #pragma unroll
        for (int j = 0; j < 4; ++j)
            acc[i][j] = (f32x4){0.f, 0.f, 0.f, 0.f};

    for (int k0 = 0; k0 < KLEN; k0 += 64) {
        #pragma unroll
        for (int it = 0; it < 4; ++it) {        // A: bf16 copy, 16B per thread per it
            int r = r0 + 32 * it;
            uint4 v = *(const uint4*)(arow[it] + k0);
            *(uint4*)(As + r * 72 + kg * 8) = v;
        }
        #pragma unroll
        for (int it = 0; it < 4; ++it) {        // B: fp32 load + cvt -> bf16
            int r = r0 + 32 * it;
            const float* s = wrow[it] + k0;
            float4 u0 = *(const float4*)s;
            float4 u1 = *(const float4*)(s + 4);
            uint4 o;
            o.x = pack2(u0.x, u0.y);
            o.y = pack2(u0.z, u0.w);
            o.z = pack2(u1.x, u1.y);
            o.w = pack2(u1.z, u1.w);
            *(uint4*)(Bs + r * 72 + kg * 8) = o;
        }
        __syncthreads();
        #pragma unroll
        for (int kk = 0; kk < 64; kk += 32) {
            bf16x8 av[4], bv[4];
            #pragma unroll
            for (int i = 0; i < 4; ++i)
                av[i] = *(const bf16x8*)(As + (wm * 64 + i * 16 + l16) * 72 + kk + quad * 8);
            #pragma unroll
            for (int j = 0; j < 4; ++j)
                bv[j] = *(const bf16x8*)(Bs + (wn * 64 + j * 16 + l16) * 72 + kk + quad * 8);
            #pragma unroll
            for (int i = 0; i < 4; ++i)
                #pragma unroll
                for (int j = 0; j < 4; ++j)
                    acc[i][j] = __builtin_amdgcn_mfma_f32_16x16x32_bf16(av[i], bv[j], acc[i][j], 0, 0, 0);
        }
        __syncthreads();
    }

    if (MODE == 3) {
        #pragma unroll
        for (int i = 0; i < 4; ++i) {
            #pragma unroll
            for (int r = 0; r < 4; ++r) {
                int p = mbase + wm * 64 + i * 16 + quad * 4 + r;
                if (p < pend) {
                    int tok = perm[p];
                    int row = rowidx[tok];
                    float sw = shw[tok], ew = expw[tok];
                    float* outr = C + (size_t)row * D_DIM;
                    #pragma unroll
                    for (int j = 0; j < 4; ++j) {
                        int gn = bn * 128 + wn * 64 + j * 16 + l16;
                        outr[gn] = outr[gn] * sw + (acc[i][j][r] + b0[gn]) * ew;
                    }
                }
            }
        }
    } else {
        #pragma unroll
        for (int i = 0; i < 4; ++i) {
            #pragma unroll
            for (int r = 0; r < 4; ++r) {
                int gm = mbase + wm * 64 + i * 16 + quad * 4 + r;
                float* outr = C + (size_t)gm * D_DIM;
                #pragma unroll
                for (int j = 0; j < 4; ++j) {
                    int gn = bn * 128 + wn * 64 + j * 16 + l16;
                    float bias = (gn < nsplit) ? b0[gn] : b1[gn - nsplit];
                    outr[gn] = acc[i][j][r] + bias;
                }
            }
        }
    }
}

extern "C" void kernel_launch(void* const* d_in, const int* in_sizes, int n_in,
                              void* d_out, int out_size, void* d_ws, size_t ws_size,
                              hipStream_t stream) {
    const float* x        = (const float*)d_in[0];
    const int*   index_b  = (const int*)d_in[1];
    const int*   index_t  = (const int*)d_in[2];
    const float* sw1      = (const float*)d_in[3];
    const float* sb1      = (const float*)d_in[4];
    const float* sw2      = (const float*)d_in[5];
    const float* sb2      = (const float*)d_in[6];
    const float* sw3      = (const float*)d_in[7];
    const float* sb3      = (const float*)d_in[8];
    const float* s_ln_g   = (const float*)d_in[9];
    const float* s_ln_b   = (const float*)d_in[10];
    const float* sg_w     = (const float*)d_in[11];
    const float* sg_b     = (const float*)d_in[12];
    const float* eg_w     = (const float*)d_in[13];
    const float* eg_b     = (const float*)d_in[14];
    const float* exp_bias = (const float*)d_in[15];
    const float* ew1      = (const float*)d_in[16];
    const float* eb1      = (const float*)d_in[17];
    const float* ew2      = (const float*)d_in[18];
    const float* eb2      = (const float*)d_in[19];
    const float* ew3      = (const float*)d_in[20];
    const float* eb3      = (const float*)d_in[21];
    const float* sel_ln_g = (const float*)d_in[22];
    const float* sel_ln_b = (const float*)d_in[23];
    float* out = (float*)d_out;
    char*  ws  = (char*)d_ws;

    // ws layout (x12/h12 alias; sh/z alias — lifetimes are disjoint in stream order)
    u16*   xb     = (u16*)(ws + 0);               //  8.39 MB  x as bf16
    float* x12    = (float*)(ws + 8388608);       // 16.78 MB  [x1|x2] fp32
    float* h12    = x12;                          //           [h1|h2] fp32 (after LN consumed x12)
    u16*   sh     = (u16*)(ws + 25165824);        //  4.19 MB  shared LN out, bf16
    u16*   z      = sh;                           //           expert LN out, bf16
    float* shw    = (float*)(ws + 29360128);
    float* expw   = shw + M_TOK;
    int*   top1   = (int*)(expw + M_TOK);
    int*   rowidx = top1 + M_TOK;
    int*   perm   = rowidx + M_TOK;
    int*   basep  = perm + MAXP;
    int*   cntp   = basep + 16;

    const int NSPLIT_NONE = 1 << 28;

    cvt_x_kernel<<<dim3(4096), dim3(256), 0, stream>>>(x, xb);
    gating_kernel<<<dim3(M_TOK), dim3(256), 0, stream>>>(x, index_b, index_t,
        sg_w, sg_b, eg_w, eg_b, exp_bias, shw, expw, top1, rowidx);
    bucket_kernel<<<dim3(1), dim3(256), 0, stream>>>(top1, basep, cntp, perm);

    // G1: x @ [sw1;sw2]^T -> x12
    gemm_kernel<0, 1024><<<dim3(8, 32), dim3(256), 0, stream>>>(
        xb, D_DIM, sw1, sw2, H_DIM, sb1, sb2, x12,
        basep, cntp, perm, rowidx, shw, expw);
    // shared silu-gate + LN -> sh (bf16)
    ln_kernel<false><<<dim3(BT_TOK), dim3(256), 0, stream>>>(x12, s_ln_g, s_ln_b, sh, basep, cntp);
    // G2: sh @ sw3^T -> d_out (all rows = shared_out + sb3)
    gemm_kernel<1, 512><<<dim3(8, 32), dim3(256), 0, stream>>>(
        sh, H_DIM, sw3, sw3, NSPLIT_NONE, sb3, sb3, out,
        basep, cntp, perm, rowidx, shw, expw);
    // E1: gathered x @ [ew1;ew2][e]^T -> h12
    gemm_kernel<2, 1024><<<dim3(8, MAXP / 128), dim3(256), 0, stream>>>(
        xb, D_DIM, ew1, ew2, H_DIM, eb1, eb2, h12,
        basep, cntp, perm, rowidx, shw, expw);
    // expert silu-gate + LN -> z (bf16, padding rows zeroed)
    ln_kernel<true><<<dim3(MAXP), dim3(256), 0, stream>>>(h12, sel_ln_g, sel_ln_b, z, basep, cntp);
    // E2: z @ ew3[e]^T, blend-scatter into d_out
    gemm_kernel<3, 512><<<dim3(8, MAXP / 128), dim3(256), 0, stream>>>(
        z, H_DIM, ew3, ew3, NSPLIT_NONE, eb3, eb3, out,
        basep, cntp, perm, rowidx, shw, expw);
}

// Round 2
// 380.932 us; speedup vs baseline: 1.0206x; 1.0206x over previous
//
#include <hip/hip_runtime.h>
#include <cstdint>

typedef unsigned short u16;
typedef __bf16 bf16x8 __attribute__((ext_vector_type(8)));
typedef float f32x4 __attribute__((ext_vector_type(4)));

#define T_SEQ  2048
#define D_DIM  1024
#define H_DIM  512
#define E_NUM  8
#define M_TOK  2048
#define BT_TOK 4096
#define MAXP   3072   // M + per-expert 128-pad worst case

static __device__ __forceinline__ u16 f2bf(float f) {
    union { float f; uint32_t u; } v; v.f = f;
    uint32_t u = v.u;
    return (u16)((u + 0x7FFFu + ((u >> 16) & 1u)) >> 16);  // RNE
}
static __device__ __forceinline__ uint32_t pack2(float a, float b) {
    return (uint32_t)f2bf(a) | ((uint32_t)f2bf(b) << 16);
}

// ---------------- generic fp32 -> bf16 convert (x and all weights) ----------------
__global__ __launch_bounds__(256) void cvt_kernel(const float* __restrict__ src,
                                                  u16* __restrict__ dst, int n4) {
    int i = blockIdx.x * 256 + threadIdx.x;
    if (i >= n4) return;
    float4 v = ((const float4*)src)[i];
    uint2 o;
    o.x = pack2(v.x, v.y);
    o.y = pack2(v.z, v.w);
    ((uint2*)dst)[i] = o;
}

// ---------------- gating: fp32 dots, sigmoid, argmax, 2-way softmax ----------------
__global__ __launch_bounds__(256)
void gating_kernel(const float* __restrict__ x,
                   const int* __restrict__ ib, const int* __restrict__ itx,
                   const float* __restrict__ sgw, const float* __restrict__ sgb,
                   const float* __restrict__ egw, const float* __restrict__ egb,
                   const float* __restrict__ ebias,
                   float* __restrict__ shw, float* __restrict__ expw,
                   int* __restrict__ top1, int* __restrict__ rowidx)
{
    int m = blockIdx.x, tid = threadIdx.x;
    __shared__ float xs[D_DIM];
    __shared__ float sc[9];
    int row = ib[m] * T_SEQ + itx[m];
    if (tid == 0) rowidx[m] = row;
    const float* xr = x + (size_t)row * D_DIM;
    ((float4*)xs)[tid] = ((const float4*)xr)[tid];
    __syncthreads();
    int lane = tid & 63, w = tid >> 6;
    for (int sidx = w; sidx < 9; sidx += 4) {
        const float* wr = (sidx == 0) ? sgw : (egw + (size_t)(sidx - 1) * D_DIM);
        float acc = 0.f;
        for (int i = lane; i < D_DIM; i += 64) acc += xs[i] * wr[i];
        #pragma unroll
        for (int o = 32; o > 0; o >>= 1) acc += __shfl_xor(acc, o);
        if (lane == 0) sc[sidx] = acc;
    }
    __syncthreads();
    if (tid == 0) {
        float ss = 1.f / (1.f + expf(-(sc[0] + sgb[0])));
        float es[E_NUM];
        float best = -1e30f; int bi = 0;
        #pragma unroll
        for (int e = 0; e < E_NUM; ++e) {
            es[e] = 1.f / (1.f + expf(-(sc[1 + e] + egb[e])));
            float t = es[e] + ebias[e];
            if (t > best) { best = t; bi = e; }   // strict > == jnp.argmax first-max
        }
        float ts = es[bi];
        shw[m]  = 1.f / (1.f + expf(ts - ss));
        expw[m] = 1.f / (1.f + expf(ss - ts));
        top1[m] = bi;
    }
}

// ---------------- bucket tokens by expert, 128-aligned bases ----------------
__global__ void bucket_kernel(const int* __restrict__ top1,
                              int* __restrict__ base, int* __restrict__ cnt,
                              int* __restrict__ perm)
{
    __shared__ int lc[E_NUM], lb[E_NUM + 1], cur[E_NUM];
    int tid = threadIdx.x;
    if (tid < E_NUM) { lc[tid] = 0; cur[tid] = 0; }
    __syncthreads();
    for (int m = tid; m < M_TOK; m += 256) atomicAdd(&lc[top1[m]], 1);
    __syncthreads();
    if (tid == 0) {
        int bacc = 0;
        for (int e = 0; e < E_NUM; ++e) { lb[e] = bacc; bacc += (lc[e] + 127) & ~127; }
        lb[E_NUM] = bacc;
    }
    __syncthreads();
    for (int m = tid; m < M_TOK; m += 256) {
        int e = top1[m];
        int pos = lb[e] + atomicAdd(&cur[e], 1);
        perm[pos] = m;
    }
    if (tid <= E_NUM) base[tid] = lb[tid];
    if (tid < E_NUM)  cnt[tid]  = lc[tid];
}

// ---------------- silu-gate + LayerNorm, sums two K-split partials, bf16 out ----------------
template<bool SEL>
__global__ __launch_bounds__(256)
void ln_kernel(const float* __restrict__ X0, const float* __restrict__ X1,
               const float* __restrict__ g, const float* __restrict__ b,
               u16* __restrict__ out,
               const int* __restrict__ base, const int* __restrict__ cnt)
{
    int m = blockIdx.x;
    int tid = threadIdx.x;
    if (SEL) {
        bool valid = false;
        int tot = base[E_NUM];
        if (m < tot) {
            int e = 0;
            while (!(m >= base[e] && m < base[e + 1])) ++e;
            valid = (m - base[e]) < cnt[e];
        }
        if (!valid) {  // zero padding rows so E2's A-tiles are clean
            out[(size_t)m * H_DIM + tid] = 0;
            out[(size_t)m * H_DIM + tid + 256] = 0;
            return;
        }
    }
    size_t ro = (size_t)m * D_DIM;
    float a0 = X0[ro + tid]         + X1[ro + tid];
    float c0 = X0[ro + H_DIM + tid] + X1[ro + H_DIM + tid];
    float a1 = X0[ro + tid + 256]         + X1[ro + tid + 256];
    float c1 = X0[ro + H_DIM + tid + 256] + X1[ro + H_DIM + tid + 256];
    float v0 = (a0 / (1.f + expf(-a0))) * c0;
    float v1 = (a1 / (1.f + expf(-a1))) * c1;
    float s = v0 + v1, s2 = v0 * v0 + v1 * v1;
    #pragma unroll
    for (int o = 32; o > 0; o >>= 1) {
        s  += __shfl_xor(s, o);
        s2 += __shfl_xor(s2, o);
    }
    __shared__ float red[8];
    int w = tid >> 6;
    if ((tid & 63) == 0) { red[w] = s; red[4 + w] = s2; }
    __syncthreads();
    s  = red[0] + red[1] + red[2] + red[3];
    s2 = red[4] + red[5] + red[6] + red[7];
    float mu  = s * (1.f / H_DIM);
    float var = s2 * (1.f / H_DIM) - mu * mu;
    float inv = rsqrtf(var + 1e-5f);
    out[(size_t)m * H_DIM + tid]       = f2bf((v0 - mu) * inv * g[tid] + b[tid]);
    out[(size_t)m * H_DIM + tid + 256] = f2bf((v1 - mu) * inv * g[tid + 256] + b[tid + 256]);
}

// ---------------- MFMA GEMM, all-bf16 operands, register-prefetch pipeline ----------------
// C[m][n] = sum_k A[m][k] * W[n][k] (+ epilogue). Tile 128 x TN, BK=64.
// MODE 0: G1  A=xb,            W=sw1b|sw2b split 512 -> x12 partial[z] (+bias at z==0)
// MODE 1: G2  A=sh,            W=sw3b                -> d_out (+sb3)
// MODE 2: E1  A=xb gathered,   W=ew1b|ew2b[e]        -> h12 partial[z] (+bias at z==0)
// MODE 3: E2  A=z bucket rows, W=ew3b[e]             -> blend d_out[row]
template<int MODE, int KLEN, int TN, int KSPLIT>
__global__ __launch_bounds__(256, 2)
void gemm_kernel(const u16* __restrict__ A, int lda,
                 const u16* __restrict__ W0, const u16* __restrict__ W1, int nsplit,
                 const float* __restrict__ b0, const float* __restrict__ b1,
                 float* __restrict__ C, size_t cstride,
                 const int* __restrict__ base, const int* __restrict__ cnt,
                 const int* __restrict__ perm, const int* __restrict__ rowidx,
                 const float* __restrict__ shw, const float* __restrict__ expw)
{
    constexpr int KC    = KLEN / KSPLIT;   // K range per block
    constexpr int NITER = KC / 64;
    constexpr int NB    = TN / 32;         // B staging iters; also j-tiles per wave

    const int tid   = threadIdx.x;
    const int bn    = blockIdx.x;
    const int bm    = blockIdx.y;
    const int bz    = (KSPLIT > 1) ? blockIdx.z : 0;
    const int mbase = bm * 128;
    const int kbase = bz * KC;

    int pend = 0;
    if (MODE >= 2) {
        const int tot = base[E_NUM];
        if (mbase >= tot) return;          // block-uniform exit before any barrier
        int e = 0;
        while (!(mbase >= base[e] && mbase < base[e + 1])) ++e;
        pend = base[e] + cnt[e];
        const size_t wstride = (size_t)H_DIM * D_DIM;
        W0 += (size_t)e * wstride;
        if (MODE == 2) W1 += (size_t)e * wstride;
        b0 += e * ((MODE == 2) ? H_DIM : D_DIM);
        if (MODE == 2) b1 += e * H_DIM;
    }

    __shared__ u16 As[128 * 72];   // stride 72: worst 2-way bank aliasing (free)
    __shared__ u16 Bs[TN * 72];

    const int kg = tid & 7;        // k-group of 8 bf16 (16B)
    const int r0 = tid >> 3;       // 0..31

    const u16* arow[4];
    const u16* wrow[NB];
    #pragma unroll
    for (int it = 0; it < 4; ++it) {
        int r = r0 + 32 * it;
        int grow;
        if (MODE == 2) {
            int p  = mbase + r;
            int pp = (p < pend) ? p : (pend - 1);   // clamp pad rows to a valid token
            grow = rowidx[perm[pp]];
        } else {
            grow = mbase + r;
        }
        arow[it] = A + (size_t)grow * lda + kbase + kg * 8;
    }
    #pragma unroll
    for (int it = 0; it < NB; ++it) {
        int n = bn * TN + r0 + 32 * it;
        wrow[it] = ((n < nsplit) ? (W0 + (size_t)n * KLEN)
                                 : (W1 + (size_t)(n - nsplit) * KLEN)) + kbase + kg * 8;
    }

    const int lane = tid & 63;
    const int wid  = tid >> 6;
    const int wm   = wid >> 1, wn = wid & 1;
    const int l16  = lane & 15, quad = lane >> 4;

    f32x4 acc[4][NB];
    #pragma unroll
    for (int i = 0; i < 4; ++i)
        #pragma unroll
        for (int j = 0; j < NB; ++j)
            acc[i][j] = (f32x4){0.f, 0.f, 0.f, 0.f};

    // prologue: tile 0 into registers
    uint4 pa[4], pb[NB];
    #pragma unroll
    for (int it = 0; it < 4; ++it)  pa[it] = *(const uint4*)(arow[it]);
    #pragma unroll
    for (int it = 0; it < NB; ++it) pb[it] = *(const uint4*)(wrow[it]);

    for (int k = 0; k < NITER; ++k) {
        #pragma unroll
        for (int it = 0; it < 4; ++it)
            *(uint4*)(As + (r0 + 32 * it) * 72 + kg * 8) = pa[it];
        #pragma unroll
        for (int it = 0; it < NB; ++it)
            *(uint4*)(Bs + (r0 + 32 * it) * 72 + kg * 8) = pb[it];
        __syncthreads();
        if (k + 1 < NITER) {               // prefetch next tile: in flight across MFMA+barrier
            int off = (k + 1) * 64;
            #pragma unroll
            for (int it = 0; it < 4; ++it)  pa[it] = *(const uint4*)(arow[it] + off);
            #pragma unroll
            for (int it = 0; it < NB; ++it) pb[it] = *(const uint4*)(wrow[it] + off);
        }
        #pragma unroll
        for (int kk = 0; kk < 64; kk += 32) {
            bf16x8 av[4], bv[NB];
            #pragma unroll
            for (int i = 0; i < 4; ++i)
                av[i] = *(const bf16x8*)(As + (wm * 64 + i * 16 + l16) * 72 + kk + quad * 8);
            #pragma unroll
            for (int j = 0; j < NB; ++j)
                bv[j] = *(const bf16x8*)(Bs + (wn * (TN / 2) + j * 16 + l16) * 72 + kk + quad * 8);
            #pragma unroll
            for (int i = 0; i < 4; ++i)
                #pragma unroll
                for (int j = 0; j < NB; ++j)
                    acc[i][j] = __builtin_amdgcn_mfma_f32_16x16x32_bf16(av[i], bv[j], acc[i][j], 0, 0, 0);
        }
        __syncthreads();
    }

    if (MODE == 3) {
        #pragma unroll
        for (int i = 0; i < 4; ++i) {
            #pragma unroll
            for (int r = 0; r < 4; ++r) {
                int p = mbase + wm * 64 + i * 16 + quad * 4 + r;
                if (p < pend) {
                    int tok = perm[p];
                    int row = rowidx[tok];
                    float sw = shw[tok], ew = expw[tok];
                    float* outr = C + (size_t)row * D_DIM;
                    #pragma unroll
                    for (int j = 0; j < NB; ++j) {
                        int gn = bn * TN + wn * (TN / 2) + j * 16 + l16;
                        outr[gn] = outr[gn] * sw + (acc[i][j][r] + b0[gn]) * ew;
                    }
                }
            }
        }
    } else {
        const bool addb = (bz == 0);
        float* Cz = C + (size_t)bz * cstride;
        #pragma unroll
        for (int i = 0; i < 4; ++i) {
            #pragma unroll
            for (int r = 0; r < 4; ++r) {
                int gm = mbase + wm * 64 + i * 16 + quad * 4 + r;
                float* outr = Cz + (size_t)gm * D_DIM;
                #pragma unroll
                for (int j = 0; j < NB; ++j) {
                    int gn = bn * TN + wn * (TN / 2) + j * 16 + l16;
                    float bias = addb ? ((gn < nsplit) ? b0[gn] : b1[gn - nsplit]) : 0.f;
                    outr[gn] = acc[i][j][r] + bias;
                }
            }
        }
    }
}

extern "C" void kernel_launch(void* const* d_in, const int* in_sizes, int n_in,
                              void* d_out, int out_size, void* d_ws, size_t ws_size,
                              hipStream_t stream) {
    const float* x        = (const float*)d_in[0];
    const int*   index_b  = (const int*)d_in[1];
    const int*   index_t  = (const int*)d_in[2];
    const float* sw1      = (const float*)d_in[3];
    const float* sb1      = (const float*)d_in[4];
    const float* sw2      = (const float*)d_in[5];
    const float* sb2      = (const float*)d_in[6];
    const float* sw3      = (const float*)d_in[7];
    const float* sb3      = (const float*)d_in[8];
    const float* s_ln_g   = (const float*)d_in[9];
    const float* s_ln_b   = (const float*)d_in[10];
    const float* sg_w     = (const float*)d_in[11];
    const float* sg_b     = (const float*)d_in[12];
    const float* eg_w     = (const float*)d_in[13];
    const float* eg_b     = (const float*)d_in[14];
    const float* exp_bias = (const float*)d_in[15];
    const float* ew1      = (const float*)d_in[16];
    const float* eb1      = (const float*)d_in[17];
    const float* ew2      = (const float*)d_in[18];
    const float* eb2      = (const float*)d_in[19];
    const float* ew3      = (const float*)d_in[20];
    const float* eb3      = (const float*)d_in[21];
    const float* sel_ln_g = (const float*)d_in[22];
    const float* sel_ln_b = (const float*)d_in[23];
    float* out = (float*)d_out;
    char*  ws  = (char*)d_ws;

    // ---- ws layout (bytes) ----
    // xb:   [0,            8388608)           x as bf16
    // wb:   [8388608,      36700160)          all weights bf16
    // x12:  [36700160,     70254592)          2 fp32 K-split partials (h12 aliases)
    // sh/z: [70254592,     74448896)          LN outputs bf16 (disjoint lifetimes)
    // misc: [74448896, ...)
    u16*   xb   = (u16*)(ws + 0);
    u16*   sw1b = (u16*)(ws + 8388608);
    u16*   sw2b = sw1b + 524288;
    u16*   sw3b = sw2b + 524288;
    u16*   ew1b = sw3b + 524288;
    u16*   ew2b = ew1b + 4194304;
    u16*   ew3b = ew2b + 4194304;
    float* x12  = (float*)(ws + 36700160);                 // + partner at +BT*D
    float* h12  = x12;                                     // + partner at +MAXP*D
    u16*   sh   = (u16*)(ws + 70254592);
    u16*   z    = sh;
    float* shw    = (float*)(ws + 74448896);
    float* expw   = shw + M_TOK;
    int*   top1   = (int*)(expw + M_TOK);
    int*   rowidx = top1 + M_TOK;
    int*   perm   = rowidx + M_TOK;
    int*   basep  = perm + MAXP;
    int*   cntp   = basep + 16;

    const int NSPLIT_NONE = 1 << 28;

    // fp32 -> bf16 conversions (x + all GEMM weights)
    cvt_kernel<<<dim3(4096), dim3(256), 0, stream>>>(x,   xb,   BT_TOK * D_DIM / 4);
    cvt_kernel<<<dim3(512),  dim3(256), 0, stream>>>(sw1, sw1b, H_DIM * D_DIM / 4);
    cvt_kernel<<<dim3(512),  dim3(256), 0, stream>>>(sw2, sw2b, H_DIM * D_DIM / 4);
    cvt_kernel<<<dim3(512),  dim3(256), 0, stream>>>(sw3, sw3b, D_DIM * H_DIM / 4);
    cvt_kernel<<<dim3(4096), dim3(256), 0, stream>>>(ew1, ew1b, E_NUM * H_DIM * D_DIM / 4);
    cvt_kernel<<<dim3(4096), dim3(256), 0, stream>>>(ew2, ew2b, E_NUM * H_DIM * D_DIM / 4);
    cvt_kernel<<<dim3(4096), dim3(256), 0, stream>>>(ew3, ew3b, E_NUM * D_DIM * H_DIM / 4);

    gating_kernel<<<dim3(M_TOK), dim3(256), 0, stream>>>(x, index_b, index_t,
        sg_w, sg_b, eg_w, eg_b, exp_bias, shw, expw, top1, rowidx);
    bucket_kernel<<<dim3(1), dim3(256), 0, stream>>>(top1, basep, cntp, perm);

    // G1: x @ [sw1;sw2]^T -> x12 partials (K-split 2)
    gemm_kernel<0, 1024, 128, 2><<<dim3(8, 32, 2), dim3(256), 0, stream>>>(
        xb, D_DIM, sw1b, sw2b, H_DIM, sb1, sb2, x12, (size_t)BT_TOK * D_DIM,
        basep, cntp, perm, rowidx, shw, expw);
    // shared silu-gate + LN (sums partials) -> sh
    ln_kernel<false><<<dim3(BT_TOK), dim3(256), 0, stream>>>(
        x12, x12 + (size_t)BT_TOK * D_DIM, s_ln_g, s_ln_b, sh, basep, cntp);
    // G2: sh @ sw3^T -> d_out (all rows)
    gemm_kernel<1, 512, 64, 1><<<dim3(16, 32, 1), dim3(256), 0, stream>>>(
        sh, H_DIM, sw3b, sw3b, NSPLIT_NONE, sb3, sb3, out, 0,
        basep, cntp, perm, rowidx, shw, expw);
    // E1: gathered x @ [ew1;ew2][e]^T -> h12 partials (K-split 2)
    gemm_kernel<2, 1024, 128, 2><<<dim3(8, MAXP / 128, 2), dim3(256), 0, stream>>>(
        xb, D_DIM, ew1b, ew2b, H_DIM, eb1, eb2, h12, (size_t)MAXP * D_DIM,
        basep, cntp, perm, rowidx, shw, expw);
    // expert silu-gate + LN (sums partials) -> z (pad rows zeroed)
    ln_kernel<true><<<dim3(MAXP), dim3(256), 0, stream>>>(
        h12, h12 + (size_t)MAXP * D_DIM, sel_ln_g, sel_ln_b, z, basep, cntp);
    // E2: z @ ew3[e]^T, blend-scatter into d_out
    gemm_kernel<3, 512, 64, 1><<<dim3(16, MAXP / 128, 1), dim3(256), 0, stream>>>(
        z, H_DIM, ew3b, ew3b, NSPLIT_NONE, eb3, eb3, out, 0,
        basep, cntp, perm, rowidx, shw, expw);
}

// Round 3
// 284.206 us; speedup vs baseline: 1.3680x; 1.3403x over previous
//
#include <hip/hip_runtime.h>
#include <cstdint>

typedef unsigned short u16;
typedef __bf16 bf16x8 __attribute__((ext_vector_type(8)));
typedef float f32x4 __attribute__((ext_vector_type(4)));

#define T_SEQ  2048
#define D_DIM  1024
#define H_DIM  512
#define E_NUM  8
#define M_TOK  2048
#define BT_TOK 4096
#define MAXP   3072   // M + per-expert 64-pad worst case, rounded up

static __device__ __forceinline__ u16 f2bf(float f) {
    union { float f; uint32_t u; } v; v.f = f;
    uint32_t u = v.u;
    return (u16)((u + 0x7FFFu + ((u >> 16) & 1u)) >> 16);  // RNE (epilogue use)
}
// round-half-up bf16 pack of two floats (2-3 VALU ops; no NaN in this data)
static __device__ __forceinline__ uint32_t pack2r(float a, float b) {
    union { float f; uint32_t u; } x, y; x.f = a; y.f = b;
    return ((x.u + 0x8000u) >> 16) | ((y.u + 0x8000u) & 0xffff0000u);
}

// ---------------- gating: fp32 dots, sigmoid, argmax, 2-way softmax ----------------
__global__ __launch_bounds__(256)
void gating_kernel(const float* __restrict__ x,
                   const int* __restrict__ ib, const int* __restrict__ itx,
                   const float* __restrict__ sgw, const float* __restrict__ sgb,
                   const float* __restrict__ egw, const float* __restrict__ egb,
                   const float* __restrict__ ebias,
                   float* __restrict__ shw, float* __restrict__ expw,
                   int* __restrict__ top1, int* __restrict__ rowidx)
{
    int m = blockIdx.x, tid = threadIdx.x;
    __shared__ float xs[D_DIM];
    __shared__ float sc[9];
    int row = ib[m] * T_SEQ + itx[m];
    if (tid == 0) rowidx[m] = row;
    const float* xr = x + (size_t)row * D_DIM;
    ((float4*)xs)[tid] = ((const float4*)xr)[tid];
    __syncthreads();
    int lane = tid & 63, w = tid >> 6;
    for (int sidx = w; sidx < 9; sidx += 4) {
        const float* wr = (sidx == 0) ? sgw : (egw + (size_t)(sidx - 1) * D_DIM);
        float acc = 0.f;
        for (int i = lane; i < D_DIM; i += 64) acc += xs[i] * wr[i];
        #pragma unroll
        for (int o = 32; o > 0; o >>= 1) acc += __shfl_xor(acc, o);
        if (lane == 0) sc[sidx] = acc;
    }
    __syncthreads();
    if (tid == 0) {
        float ss = 1.f / (1.f + expf(-(sc[0] + sgb[0])));
        float es[E_NUM];
        float best = -1e30f; int bi = 0;
        #pragma unroll
        for (int e = 0; e < E_NUM; ++e) {
            es[e] = 1.f / (1.f + expf(-(sc[1 + e] + egb[e])));
            float t = es[e] + ebias[e];
            if (t > best) { best = t; bi = e; }   // strict > == jnp.argmax first-max
        }
        float ts = es[bi];
        shw[m]  = 1.f / (1.f + expf(ts - ss));
        expw[m] = 1.f / (1.f + expf(ss - ts));
        top1[m] = bi;
    }
}

// ---------------- bucket tokens by expert, 64-aligned bases ----------------
__global__ void bucket_kernel(const int* __restrict__ top1,
                              int* __restrict__ base, int* __restrict__ cnt,
                              int* __restrict__ perm)
{
    __shared__ int lc[E_NUM], lb[E_NUM + 1], cur[E_NUM];
    int tid = threadIdx.x;
    if (tid < E_NUM) { lc[tid] = 0; cur[tid] = 0; }
    __syncthreads();
    for (int m = tid; m < M_TOK; m += 256) atomicAdd(&lc[top1[m]], 1);
    __syncthreads();
    if (tid == 0) {
        int bacc = 0;
        for (int e = 0; e < E_NUM; ++e) { lb[e] = bacc; bacc += (lc[e] + 63) & ~63; }
        lb[E_NUM] = bacc;
    }
    __syncthreads();
    for (int m = tid; m < M_TOK; m += 256) {
        int e = top1[m];
        int pos = lb[e] + atomicAdd(&cur[e], 1);
        perm[pos] = m;
    }
    if (tid <= E_NUM) base[tid] = lb[tid];
    if (tid < E_NUM)  cnt[tid]  = lc[tid];
}

// ---------------- silu-gate + LayerNorm, sums two K-split partials, bf16 out ----------------
template<bool SEL>
__global__ __launch_bounds__(256)
void ln_kernel(const float* __restrict__ X0, const float* __restrict__ X1,
               const float* __restrict__ g, const float* __restrict__ b,
               u16* __restrict__ out,
               const int* __restrict__ base, const int* __restrict__ cnt)
{
    int m = blockIdx.x;
    int tid = threadIdx.x;
    if (SEL) {
        bool valid = false;
        int tot = base[E_NUM];
        if (m < tot) {
            int e = 0;
            while (!(m >= base[e] && m < base[e + 1])) ++e;
            valid = (m - base[e]) < cnt[e];
        }
        if (!valid) {  // zero padding rows so E2's A-tiles are clean
            out[(size_t)m * H_DIM + tid] = 0;
            out[(size_t)m * H_DIM + tid + 256] = 0;
            return;
        }
    }
    size_t ro = (size_t)m * D_DIM;
    float a0 = X0[ro + tid]         + X1[ro + tid];
    float c0 = X0[ro + H_DIM + tid] + X1[ro + H_DIM + tid];
    float a1 = X0[ro + tid + 256]         + X1[ro + tid + 256];
    float c1 = X0[ro + H_DIM + tid + 256] + X1[ro + H_DIM + tid + 256];
    float v0 = (a0 / (1.f + expf(-a0))) * c0;
    float v1 = (a1 / (1.f + expf(-a1))) * c1;
    float s = v0 + v1, s2 = v0 * v0 + v1 * v1;
    #pragma unroll
    for (int o = 32; o > 0; o >>= 1) {
        s  += __shfl_xor(s, o);
        s2 += __shfl_xor(s2, o);
    }
    __shared__ float red[8];
    int w = tid >> 6;
    if ((tid & 63) == 0) { red[w] = s; red[4 + w] = s2; }
    __syncthreads();
    s  = red[0] + red[1] + red[2] + red[3];
    s2 = red[4] + red[5] + red[6] + red[7];
    float mu  = s * (1.f / H_DIM);
    float var = s2 * (1.f / H_DIM) - mu * mu;
    float inv = rsqrtf(var + 1e-5f);
    out[(size_t)m * H_DIM + tid]       = f2bf((v0 - mu) * inv * g[tid] + b[tid]);
    out[(size_t)m * H_DIM + tid + 256] = f2bf((v1 - mu) * inv * g[tid + 256] + b[tid + 256]);
}

// ---------------- MFMA GEMM, 64x64 tile, fp32->bf16 in-register staging ----------------
// C[m][n] = sum_k A[m][k] * W[n][k] (+ epilogue). BK=64, register prefetch depth 1.
// MODE 0: G1  A=x fp32,         W=sw1|sw2 split 512 -> x12 partial[z] (+bias at z==0)
// MODE 1: G2  A=sh bf16,        W=sw3               -> d_out (+sb3)
// MODE 2: E1  A=x fp32 gathered W=ew1|ew2[e]        -> h12 partial[z] (+bias at z==0)
// MODE 3: E2  A=z bf16 buckets, W=ew3[e]            -> blend d_out[row]
template<int MODE, int KLEN, int KSPLIT, bool A_BF16>
__global__ __launch_bounds__(256, 4)
void gemm_kernel(const void* __restrict__ Av, int lda,
                 const float* __restrict__ W0, const float* __restrict__ W1, int nsplit,
                 const float* __restrict__ b0, const float* __restrict__ b1,
                 float* __restrict__ C, size_t cstride,
                 const int* __restrict__ base, const int* __restrict__ cnt,
                 const int* __restrict__ perm, const int* __restrict__ rowidx,
                 const float* __restrict__ shw, const float* __restrict__ expw)
{
    constexpr int KC    = KLEN / KSPLIT;
    constexpr int NITER = KC / 64;

    const int tid   = threadIdx.x;
    const int bn    = blockIdx.x;
    const int bm    = blockIdx.y;
    const int bz    = (KSPLIT > 1) ? blockIdx.z : 0;
    const int mbase = bm * 64;
    const int kbase = bz * KC;

    int pend = 0;
    if (MODE >= 2) {
        const int tot = base[E_NUM];
        if (mbase >= tot) return;          // block-uniform exits before any barrier
        int e = 0;
        while (!(mbase >= base[e] && mbase < base[e + 1])) ++e;
        pend = base[e] + cnt[e];
        if (mbase >= pend) return;         // all-pad block: nobody reads its output
        const size_t wstride = (size_t)H_DIM * D_DIM;
        W0 += (size_t)e * wstride;
        if (MODE == 2) W1 += (size_t)e * wstride;
        b0 += e * ((MODE == 2) ? H_DIM : D_DIM);
        if (MODE == 2) b1 += e * H_DIM;
    }

    __shared__ u16 As[64 * 72];   // stride 72: modest aliasing, measured cheap
    __shared__ u16 Bs[64 * 72];

    const int kq = tid & 3;       // 16-elem k-chunk
    const int r  = tid >> 2;      // 0..63 (A row / W row)

    // K-invariant row pointers
    const float* af = nullptr; const u16* ab = nullptr;
    if (MODE == 2) {
        int p  = mbase + r;
        int pp = (p < pend) ? p : (pend - 1);
        int grow = rowidx[perm[pp]];
        af = (const float*)Av + (size_t)grow * lda + kbase + kq * 16;
    } else if (A_BF16) {
        ab = (const u16*)Av + (size_t)(mbase + r) * lda + kbase + kq * 16;
    } else {
        af = (const float*)Av + (size_t)(mbase + r) * lda + kbase + kq * 16;
    }
    int n = bn * 64 + r;
    const float* wf = ((n < nsplit) ? (W0 + (size_t)n * KLEN)
                                    : (W1 + (size_t)(n - nsplit) * KLEN)) + kbase + kq * 16;

    const int lane = tid & 63;
    const int wid  = tid >> 6;
    const int wm   = wid >> 1, wn = wid & 1;
    const int l16  = lane & 15, quad = lane >> 4;

    f32x4 acc[2][2];
    #pragma unroll
    for (int i = 0; i < 2; ++i)
        #pragma unroll
        for (int j = 0; j < 2; ++j)
            acc[i][j] = (f32x4){0.f, 0.f, 0.f, 0.f};

    // prefetch registers: 16 k-elems per operand per thread
    float4 paf[4]; uint4 pau[2]; float4 pbf[4];
    #pragma unroll
    for (int q = 0; q < 4; ++q) pbf[q] = ((const float4*)wf)[q];
    if (A_BF16) {
        #pragma unroll
        for (int q = 0; q < 2; ++q) pau[q] = ((const uint4*)ab)[q];
    } else {
        #pragma unroll
        for (int q = 0; q < 4; ++q) paf[q] = ((const float4*)af)[q];
    }

    for (int k = 0; k < NITER; ++k) {
        // convert + LDS store (waits on prefetched loads)
        uint4 sa0, sa1, sb0, sb1;
        if (A_BF16) { sa0 = pau[0]; sa1 = pau[1]; }
        else {
            sa0.x = pack2r(paf[0].x, paf[0].y); sa0.y = pack2r(paf[0].z, paf[0].w);
            sa0.z = pack2r(paf[1].x, paf[1].y); sa0.w = pack2r(paf[1].z, paf[1].w);
            sa1.x = pack2r(paf[2].x, paf[2].y); sa1.y = pack2r(paf[2].z, paf[2].w);
            sa1.z = pack2r(paf[3].x, paf[3].y); sa1.w = pack2r(paf[3].z, paf[3].w);
        }
        sb0.x = pack2r(pbf[0].x, pbf[0].y); sb0.y = pack2r(pbf[0].z, pbf[0].w);
        sb0.z = pack2r(pbf[1].x, pbf[1].y); sb0.w = pack2r(pbf[1].z, pbf[1].w);
        sb1.x = pack2r(pbf[2].x, pbf[2].y); sb1.y = pack2r(pbf[2].z, pbf[2].w);
        sb1.z = pack2r(pbf[3].x, pbf[3].y); sb1.w = pack2r(pbf[3].z, pbf[3].w);
        *(uint4*)(As + r * 72 + kq * 16)     = sa0;
        *(uint4*)(As + r * 72 + kq * 16 + 8) = sa1;
        *(uint4*)(Bs + r * 72 + kq * 16)     = sb0;
        *(uint4*)(Bs + r * 72 + kq * 16 + 8) = sb1;
        __syncthreads();
        if (k + 1 < NITER) {   // prefetch next K-tile: in flight across MFMA + barrier
            int off = (k + 1) * 64;
            #pragma unroll
            for (int q = 0; q < 4; ++q) pbf[q] = *(const float4*)(wf + off + q * 4);
            if (A_BF16) {
                #pragma unroll
                for (int q = 0; q < 2; ++q) pau[q] = *(const uint4*)(ab + off + q * 8);
            } else {
                #pragma unroll
                for (int q = 0; q < 4; ++q) paf[q] = *(const float4*)(af + off + q * 4);
            }
        }
        #pragma unroll
        for (int kk = 0; kk < 64; kk += 32) {
            bf16x8 av[2], bv[2];
            #pragma unroll
            for (int i = 0; i < 2; ++i)
                av[i] = *(const bf16x8*)(As + (wm * 32 + i * 16 + l16) * 72 + kk + quad * 8);
            #pragma unroll
            for (int j = 0; j < 2; ++j)
                bv[j] = *(const bf16x8*)(Bs + (wn * 32 + j * 16 + l16) * 72 + kk + quad * 8);
            #pragma unroll
            for (int i = 0; i < 2; ++i)
                #pragma unroll
                for (int j = 0; j < 2; ++j)
                    acc[i][j] = __builtin_amdgcn_mfma_f32_16x16x32_bf16(av[i], bv[j], acc[i][j], 0, 0, 0);
        }
        __syncthreads();
    }

    if (MODE == 3) {
        #pragma unroll
        for (int i = 0; i < 2; ++i) {
            #pragma unroll
            for (int rr = 0; rr < 4; ++rr) {
                int p = mbase + wm * 32 + i * 16 + quad * 4 + rr;
                if (p < pend) {
                    int tok = perm[p];
                    int row = rowidx[tok];
                    float sw = shw[tok], ew = expw[tok];
                    float* outr = C + (size_t)row * D_DIM;
                    #pragma unroll
                    for (int j = 0; j < 2; ++j) {
                        int gn = bn * 64 + wn * 32 + j * 16 + l16;
                        outr[gn] = outr[gn] * sw + (acc[i][j][rr] + b0[gn]) * ew;
                    }
                }
            }
        }
    } else {
        const bool addb = (bz == 0);
        float* Cz = C + (size_t)bz * cstride;
        #pragma unroll
        for (int i = 0; i < 2; ++i) {
            #pragma unroll
            for (int rr = 0; rr < 4; ++rr) {
                int gm = mbase + wm * 32 + i * 16 + quad * 4 + rr;
                float* outr = Cz + (size_t)gm * D_DIM;
                #pragma unroll
                for (int j = 0; j < 2; ++j) {
                    int gn = bn * 64 + wn * 32 + j * 16 + l16;
                    float bias = addb ? ((gn < nsplit) ? b0[gn] : b1[gn - nsplit]) : 0.f;
                    outr[gn] = acc[i][j][rr] + bias;
                }
            }
        }
    }
}

extern "C" void kernel_launch(void* const* d_in, const int* in_sizes, int n_in,
                              void* d_out, int out_size, void* d_ws, size_t ws_size,
                              hipStream_t stream) {
    const float* x        = (const float*)d_in[0];
    const int*   index_b  = (const int*)d_in[1];
    const int*   index_t  = (const int*)d_in[2];
    const float* sw1      = (const float*)d_in[3];
    const float* sb1      = (const float*)d_in[4];
    const float* sw2      = (const float*)d_in[5];
    const float* sb2      = (const float*)d_in[6];
    const float* sw3      = (const float*)d_in[7];
    const float* sb3      = (const float*)d_in[8];
    const float* s_ln_g   = (const float*)d_in[9];
    const float* s_ln_b   = (const float*)d_in[10];
    const float* sg_w     = (const float*)d_in[11];
    const float* sg_b     = (const float*)d_in[12];
    const float* eg_w     = (const float*)d_in[13];
    const float* eg_b     = (const float*)d_in[14];
    const float* exp_bias = (const float*)d_in[15];
    const float* ew1      = (const float*)d_in[16];
    const float* eb1      = (const float*)d_in[17];
    const float* ew2      = (const float*)d_in[18];
    const float* eb2      = (const float*)d_in[19];
    const float* ew3      = (const float*)d_in[20];
    const float* eb3      = (const float*)d_in[21];
    const float* sel_ln_g = (const float*)d_in[22];
    const float* sel_ln_b = (const float*)d_in[23];
    float* out = (float*)d_out;
    char*  ws  = (char*)d_ws;

    // ---- ws layout ----
    // x12: [0, 33554432)           2 fp32 K-split partials, 4096x1024 each
    // h12: aliases x12             2 fp32 partials, 3072x1024 each (x12 dead by then)
    // sh : [33554432, 37748736)    4096x512 bf16 (z aliases; sh dead by then)
    // misc: [37748736, ...)
    float* x12  = (float*)(ws + 0);
    float* h12  = x12;
    u16*   sh   = (u16*)(ws + 33554432);
    u16*   z    = sh;
    float* shw    = (float*)(ws + 37748736);
    float* expw   = shw + M_TOK;
    int*   top1   = (int*)(expw + M_TOK);
    int*   rowidx = top1 + M_TOK;
    int*   perm   = rowidx + M_TOK;
    int*   basep  = perm + MAXP;
    int*   cntp   = basep + 16;

    const int NSPLIT_NONE = 1 << 28;

    gating_kernel<<<dim3(M_TOK), dim3(256), 0, stream>>>(x, index_b, index_t,
        sg_w, sg_b, eg_w, eg_b, exp_bias, shw, expw, top1, rowidx);
    bucket_kernel<<<dim3(1), dim3(256), 0, stream>>>(top1, basep, cntp, perm);

    // G1: x @ [sw1;sw2]^T -> x12 partials (K-split 2). 2048 blocks.
    gemm_kernel<0, 1024, 2, false><<<dim3(16, 64, 2), dim3(256), 0, stream>>>(
        x, D_DIM, sw1, sw2, H_DIM, sb1, sb2, x12, (size_t)BT_TOK * D_DIM,
        basep, cntp, perm, rowidx, shw, expw);
    // shared silu-gate + LN (sums partials) -> sh
    ln_kernel<false><<<dim3(BT_TOK), dim3(256), 0, stream>>>(
        x12, x12 + (size_t)BT_TOK * D_DIM, s_ln_g, s_ln_b, sh, basep, cntp);
    // G2: sh @ sw3^T -> d_out (all rows). 1024 blocks.
    gemm_kernel<1, 512, 1, true><<<dim3(16, 64, 1), dim3(256), 0, stream>>>(
        sh, H_DIM, sw3, sw3, NSPLIT_NONE, sb3, sb3, out, 0,
        basep, cntp, perm, rowidx, shw, expw);
    // E1: gathered x @ [ew1;ew2][e]^T -> h12 partials (K-split 2). <=1536 blocks.
    gemm_kernel<2, 1024, 2, false><<<dim3(16, MAXP / 64, 2), dim3(256), 0, stream>>>(
        x, D_DIM, ew1, ew2, H_DIM, eb1, eb2, h12, (size_t)MAXP * D_DIM,
        basep, cntp, perm, rowidx, shw, expw);
    // expert silu-gate + LN (sums partials) -> z (pad rows zeroed)
    ln_kernel<true><<<dim3(MAXP), dim3(256), 0, stream>>>(
        h12, h12 + (size_t)MAXP * D_DIM, sel_ln_g, sel_ln_b, z, basep, cntp);
    // E2: z @ ew3[e]^T, blend-scatter into d_out. <=768 blocks.
    gemm_kernel<3, 512, 1, true><<<dim3(16, MAXP / 64, 1), dim3(256), 0, stream>>>(
        z, H_DIM, ew3, ew3, NSPLIT_NONE, eb3, eb3, out, 0,
        basep, cntp, perm, rowidx, shw, expw);
}

// Round 4
// 248.214 us; speedup vs baseline: 1.5664x; 1.1450x over previous
//
#include <hip/hip_runtime.h>
#include <cstdint>

typedef unsigned short u16;
typedef __bf16 bf16x8 __attribute__((ext_vector_type(8)));
typedef float f32x4 __attribute__((ext_vector_type(4)));

#define T_SEQ  2048
#define D_DIM  1024
#define H_DIM  512
#define E_NUM  8
#define M_TOK  2048
#define BT_TOK 4096
#define MAXP   3072   // M + per-expert 64-pad worst case

static __device__ __forceinline__ u16 f2bf(float f) {
    union { float f; uint32_t u; } v; v.f = f;
    uint32_t u = v.u;
    return (u16)((u + 0x7FFFu + ((u >> 16) & 1u)) >> 16);  // RNE
}
static __device__ __forceinline__ uint32_t pack2(float a, float b) {
    return (uint32_t)f2bf(a) | ((uint32_t)f2bf(b) << 16);
}

// async global -> LDS, 16B per lane. lptr must be the wave-uniform base;
// HW scatters lane i to lptr + i*16 (m104/m108).
static __device__ __forceinline__ void gl_lds16(const u16* g, u16* l) {
    __builtin_amdgcn_global_load_lds(
        (const __attribute__((address_space(1))) uint32_t*)g,
        (__attribute__((address_space(3))) uint32_t*)l, 16, 0, 0);
}

// ---------------- single fused fp32 -> bf16 convert: x + all 6 weight tensors ----------------
// f4-unit segment offsets: x 1048576 | sw1/sw2/sw3 131072 each | ew1/ew2/ew3 1048576 each
__global__ __launch_bounds__(256)
void cvt_all_kernel(const float* __restrict__ x,
                    const float* __restrict__ sw1, const float* __restrict__ sw2,
                    const float* __restrict__ sw3,
                    const float* __restrict__ ew1, const float* __restrict__ ew2,
                    const float* __restrict__ ew3,
                    u16* __restrict__ xb,
                    u16* __restrict__ sw1b, u16* __restrict__ sw2b, u16* __restrict__ sw3b,
                    u16* __restrict__ ew1b, u16* __restrict__ ew2b, u16* __restrict__ ew3b)
{
    long i = (long)blockIdx.x * 256 + threadIdx.x;   // grid covers 4587520 exactly
    const float* s; u16* d; long off;
    if      (i < 1048576) { s = x;   d = xb;   off = i; }
    else if (i < 1179648) { s = sw1; d = sw1b; off = i - 1048576; }
    else if (i < 1310720) { s = sw2; d = sw2b; off = i - 1179648; }
    else if (i < 1441792) { s = sw3; d = sw3b; off = i - 1310720; }
    else if (i < 2490368) { s = ew1; d = ew1b; off = i - 1441792; }
    else if (i < 3538944) { s = ew2; d = ew2b; off = i - 2490368; }
    else                  { s = ew3; d = ew3b; off = i - 3538944; }
    float4 v = ((const float4*)s)[off];
    uint2 o;
    o.x = pack2(v.x, v.y);
    o.y = pack2(v.z, v.w);
    ((uint2*)d)[off] = o;
}

// ---------------- gating: fp32 dots, sigmoid, argmax, 2-way softmax ----------------
__global__ __launch_bounds__(256)
void gating_kernel(const float* __restrict__ x,
                   const int* __restrict__ ib, const int* __restrict__ itx,
                   const float* __restrict__ sgw, const float* __restrict__ sgb,
                   const float* __restrict__ egw, const float* __restrict__ egb,
                   const float* __restrict__ ebias,
                   float* __restrict__ shw, float* __restrict__ expw,
                   int* __restrict__ top1, int* __restrict__ rowidx)
{
    int m = blockIdx.x, tid = threadIdx.x;
    __shared__ float xs[D_DIM];
    __shared__ float sc[9];
    int row = ib[m] * T_SEQ + itx[m];
    if (tid == 0) rowidx[m] = row;
    const float* xr = x + (size_t)row * D_DIM;
    ((float4*)xs)[tid] = ((const float4*)xr)[tid];
    __syncthreads();
    int lane = tid & 63, w = tid >> 6;
    for (int sidx = w; sidx < 9; sidx += 4) {
        const float* wr = (sidx == 0) ? sgw : (egw + (size_t)(sidx - 1) * D_DIM);
        float acc = 0.f;
        for (int i = lane; i < D_DIM; i += 64) acc += xs[i] * wr[i];
        #pragma unroll
        for (int o = 32; o > 0; o >>= 1) acc += __shfl_xor(acc, o);
        if (lane == 0) sc[sidx] = acc;
    }
    __syncthreads();
    if (tid == 0) {
        float ss = 1.f / (1.f + expf(-(sc[0] + sgb[0])));
        float es[E_NUM];
        float best = -1e30f; int bi = 0;
        #pragma unroll
        for (int e = 0; e < E_NUM; ++e) {
            es[e] = 1.f / (1.f + expf(-(sc[1 + e] + egb[e])));
            float t = es[e] + ebias[e];
            if (t > best) { best = t; bi = e; }   // strict > == jnp.argmax first-max
        }
        float ts = es[bi];
        shw[m]  = 1.f / (1.f + expf(ts - ss));
        expw[m] = 1.f / (1.f + expf(ss - ts));
        top1[m] = bi;
    }
}

// ---------------- bucket tokens by expert, 64-aligned bases ----------------
__global__ void bucket_kernel(const int* __restrict__ top1,
                              int* __restrict__ base, int* __restrict__ cnt,
                              int* __restrict__ perm)
{
    __shared__ int lc[E_NUM], lb[E_NUM + 1], cur[E_NUM];
    int tid = threadIdx.x;
    if (tid < E_NUM) { lc[tid] = 0; cur[tid] = 0; }
    __syncthreads();
    for (int m = tid; m < M_TOK; m += 256) atomicAdd(&lc[top1[m]], 1);
    __syncthreads();
    if (tid == 0) {
        int bacc = 0;
        for (int e = 0; e < E_NUM; ++e) { lb[e] = bacc; bacc += (lc[e] + 63) & ~63; }
        lb[E_NUM] = bacc;
    }
    __syncthreads();
    for (int m = tid; m < M_TOK; m += 256) {
        int e = top1[m];
        int pos = lb[e] + atomicAdd(&cur[e], 1);
        perm[pos] = m;
    }
    if (tid <= E_NUM) base[tid] = lb[tid];
    if (tid < E_NUM)  cnt[tid]  = lc[tid];
}

// ---------------- silu-gate + LayerNorm, fp32 in -> bf16 out ----------------
template<bool SEL>
__global__ __launch_bounds__(256)
void ln_kernel(const float* __restrict__ X,
               const float* __restrict__ g, const float* __restrict__ b,
               u16* __restrict__ out,
               const int* __restrict__ base, const int* __restrict__ cnt)
{
    int m = blockIdx.x;
    int tid = threadIdx.x;
    if (SEL) {
        bool valid = false;
        int tot = base[E_NUM];
        if (m < tot) {
            int e = 0;
            while (!(m >= base[e] && m < base[e + 1])) ++e;
            valid = (m - base[e]) < cnt[e];
        }
        if (!valid) {  // zero padding rows so E2's A-tiles are clean
            out[(size_t)m * H_DIM + tid] = 0;
            out[(size_t)m * H_DIM + tid + 256] = 0;
            return;
        }
    }
    const float* row = X + (size_t)m * D_DIM;   // [0:512]=x1, [512:1024]=x2
    float a0 = row[tid],       c0 = row[H_DIM + tid];
    float a1 = row[tid + 256], c1 = row[H_DIM + tid + 256];
    float v0 = (a0 / (1.f + expf(-a0))) * c0;
    float v1 = (a1 / (1.f + expf(-a1))) * c1;
    float s = v0 + v1, s2 = v0 * v0 + v1 * v1;
    #pragma unroll
    for (int o = 32; o > 0; o >>= 1) {
        s  += __shfl_xor(s, o);
        s2 += __shfl_xor(s2, o);
    }
    __shared__ float red[8];
    int w = tid >> 6;
    if ((tid & 63) == 0) { red[w] = s; red[4 + w] = s2; }
    __syncthreads();
    s  = red[0] + red[1] + red[2] + red[3];
    s2 = red[4] + red[5] + red[6] + red[7];
    float mu  = s * (1.f / H_DIM);
    float var = s2 * (1.f / H_DIM) - mu * mu;
    float inv = rsqrtf(var + 1e-5f);
    out[(size_t)m * H_DIM + tid]       = f2bf((v0 - mu) * inv * g[tid] + b[tid]);
    out[(size_t)m * H_DIM + tid + 256] = f2bf((v1 - mu) * inv * g[tid + 256] + b[tid + 256]);
}

// ---------------- MFMA GEMM: 64x128 tile, BK=64, global_load_lds staging ----------------
// C[m][n] = sum_k A[m][k] * W[n][k] (+ epilogue). All operands bf16.
// LDS: A 64 rows x 128B (8KB) | B 128 rows x 128B (16KB), 16B chunks XOR-swizzled by row
// K-start rotated per block to spread concurrent traffic across memory channels.
// MODE 0: G1  A=xb,           W=sw1b|sw2b split 512 -> x12 (+sb1|sb2)
// MODE 1: G2  A=sh,           W=sw3b                -> d_out (+sb3)
// MODE 2: E1  A=xb gathered,  W=ew1b|ew2b[e]        -> h12 (+eb1|eb2[e])
// MODE 3: E2  A=z bucketed,   W=ew3b[e]             -> blend d_out[row]
template<int MODE, int KLEN>
__global__ __launch_bounds__(256, 4)
void gemm_kernel(const u16* __restrict__ A, int lda,
                 const u16* __restrict__ W0, const u16* __restrict__ W1, int nsplit,
                 const float* __restrict__ b0, const float* __restrict__ b1,
                 float* __restrict__ C,
                 const int* __restrict__ base, const int* __restrict__ cnt,
                 const int* __restrict__ perm, const int* __restrict__ rowidx,
                 const float* __restrict__ shw, const float* __restrict__ expw)
{
    constexpr int NITER = KLEN / 64;
    const int tid   = threadIdx.x;
    const int bn    = blockIdx.x;
    const int bm    = blockIdx.y;
    const int mbase = bm * 64;

    int pend = 0;
    if (MODE >= 2) {
        const int tot = base[E_NUM];
        if (mbase >= tot) return;          // block-uniform exits before any barrier
        int e = 0;
        while (!(mbase >= base[e] && mbase < base[e + 1])) ++e;
        pend = base[e] + cnt[e];
        if (mbase >= pend) return;         // all-pad tile: output never read
        const size_t wstride = (size_t)H_DIM * D_DIM;
        W0 += (size_t)e * wstride;
        if (MODE == 2) W1 += (size_t)e * wstride;
        b0 += e * ((MODE == 2) ? H_DIM : D_DIM);
        if (MODE == 2) b1 += e * H_DIM;
    }

    __shared__ __align__(16) u16 lds[(64 + 128) * 64];   // 24 KB

    const int w  = tid >> 6;        // wave 0..3
    const int l  = tid & 63;
    const int sr = tid >> 3;        // staging row-in-round 0..31 (== w*8 + (l>>3))
    const int sc = tid & 7;         // staging 16B-chunk 0..7

    // K-invariant global row pointers. Physical LDS chunk p holds logical chunk p^(r&7),
    // so lane (r, p=sc) fetches logical chunk sc^(r&7).
    const u16* agp[2];
    #pragma unroll
    for (int t = 0; t < 2; ++t) {
        int r = t * 32 + sr;
        int grow;
        if (MODE == 2) {
            int p  = mbase + r;
            int pp = (p < pend) ? p : (pend - 1);   // clamp pad rows to a valid token
            grow = rowidx[perm[pp]];
        } else {
            grow = mbase + r;
        }
        agp[t] = A + (size_t)grow * lda + (sc ^ (r & 7)) * 8;
    }
    const u16* bgp[4];
    #pragma unroll
    for (int t = 0; t < 4; ++t) {
        int r = t * 32 + sr;
        int n = bn * 128 + r;
        bgp[t] = ((n < nsplit) ? (W0 + (size_t)n * KLEN)
                               : (W1 + (size_t)(n - nsplit) * KLEN)) + (sc ^ (r & 7)) * 8;
    }

    const int l16 = l & 15, quad = l >> 4;
    const int wm = w >> 1, wn = w & 1;

    // K-invariant LDS read byte-offsets (logical chunk q = kx*4+quad, phys = q^(R&7))
    int avo[2][2], bvo[4][2];
    #pragma unroll
    for (int i = 0; i < 2; ++i) {
        int R = wm * 32 + i * 16 + l16;
        #pragma unroll
        for (int kx = 0; kx < 2; ++kx)
            avo[i][kx] = R * 128 + (((kx * 4 + quad) ^ (R & 7)) * 16);
    }
    #pragma unroll
    for (int j = 0; j < 4; ++j) {
        int R = wn * 64 + j * 16 + l16;
        #pragma unroll
        for (int kx = 0; kx < 2; ++kx)
            bvo[j][kx] = 8192 + R * 128 + (((kx * 4 + quad) ^ (R & 7)) * 16);
    }

    f32x4 acc[2][4];
    #pragma unroll
    for (int i = 0; i < 2; ++i)
        #pragma unroll
        for (int j = 0; j < 4; ++j)
            acc[i][j] = (f32x4){0.f, 0.f, 0.f, 0.f};

    const int kstart = (bm + bn * 3) & (NITER - 1);   // channel-spread rotation
    const char* ldsc = (const char*)lds;

    for (int it = 0; it < NITER; ++it) {
        int k0 = ((it + kstart) & (NITER - 1)) * 64;
        #pragma unroll
        for (int t = 0; t < 2; ++t)       // A tile: 2 x (4KB per 256 threads)
            gl_lds16(agp[t] + k0, lds + t * 2048 + w * 512);
        #pragma unroll
        for (int t = 0; t < 4; ++t)       // B tile: 4 rounds
            gl_lds16(bgp[t] + k0, lds + 4096 + t * 2048 + w * 512);
        __syncthreads();                  // drains vmcnt for the DMA writes
        #pragma unroll
        for (int kx = 0; kx < 2; ++kx) {
            bf16x8 av[2], bv[4];
            #pragma unroll
            for (int i = 0; i < 2; ++i)
                av[i] = *(const bf16x8*)(ldsc + avo[i][kx]);
            #pragma unroll
            for (int j = 0; j < 4; ++j)
                bv[j] = *(const bf16x8*)(ldsc + bvo[j][kx]);
            #pragma unroll
            for (int i = 0; i < 2; ++i)
                #pragma unroll
                for (int j = 0; j < 4; ++j)
                    acc[i][j] = __builtin_amdgcn_mfma_f32_16x16x32_bf16(av[i], bv[j], acc[i][j], 0, 0, 0);
        }
        __syncthreads();
    }

    if (MODE == 3) {
        #pragma unroll
        for (int i = 0; i < 2; ++i) {
            #pragma unroll
            for (int rr = 0; rr < 4; ++rr) {
                int p = mbase + wm * 32 + i * 16 + quad * 4 + rr;
                if (p < pend) {
                    int tok = perm[p];
                    int row = rowidx[tok];
                    float sw = shw[tok], ew = expw[tok];
                    float* outr = C + (size_t)row * D_DIM;
                    #pragma unroll
                    for (int j = 0; j < 4; ++j) {
                        int gn = bn * 128 + wn * 64 + j * 16 + l16;
                        outr[gn] = outr[gn] * sw + (acc[i][j][rr] + b0[gn]) * ew;
                    }
                }
            }
        }
    } else {
        #pragma unroll
        for (int i = 0; i < 2; ++i) {
            #pragma unroll
            for (int rr = 0; rr < 4; ++rr) {
                int gm = mbase + wm * 32 + i * 16 + quad * 4 + rr;
                float* outr = C + (size_t)gm * D_DIM;
                #pragma unroll
                for (int j = 0; j < 4; ++j) {
                    int gn = bn * 128 + wn * 64 + j * 16 + l16;
                    float bias = (gn < nsplit) ? b0[gn] : b1[gn - nsplit];
                    outr[gn] = acc[i][j][rr] + bias;
                }
            }
        }
    }
}

extern "C" void kernel_launch(void* const* d_in, const int* in_sizes, int n_in,
                              void* d_out, int out_size, void* d_ws, size_t ws_size,
                              hipStream_t stream) {
    const float* x        = (const float*)d_in[0];
    const int*   index_b  = (const int*)d_in[1];
    const int*   index_t  = (const int*)d_in[2];
    const float* sw1      = (const float*)d_in[3];
    const float* sb1      = (const float*)d_in[4];
    const float* sw2      = (const float*)d_in[5];
    const float* sb2      = (const float*)d_in[6];
    const float* sw3      = (const float*)d_in[7];
    const float* sb3      = (const float*)d_in[8];
    const float* s_ln_g   = (const float*)d_in[9];
    const float* s_ln_b   = (const float*)d_in[10];
    const float* sg_w     = (const float*)d_in[11];
    const float* sg_b     = (const float*)d_in[12];
    const float* eg_w     = (const float*)d_in[13];
    const float* eg_b     = (const float*)d_in[14];
    const float* exp_bias = (const float*)d_in[15];
    const float* ew1      = (const float*)d_in[16];
    const float* eb1      = (const float*)d_in[17];
    const float* ew2      = (const float*)d_in[18];
    const float* eb2      = (const float*)d_in[19];
    const float* ew3      = (const float*)d_in[20];
    const float* eb3      = (const float*)d_in[21];
    const float* sel_ln_g = (const float*)d_in[22];
    const float* sel_ln_b = (const float*)d_in[23];
    float* out = (float*)d_out;
    char*  ws  = (char*)d_ws;

    // ---- ws layout (bytes) ----
    u16*   xb   = (u16*)(ws + 0);              //  8 MB  x bf16
    u16*   sw1b = (u16*)(ws + 8388608);        //  1 MB
    u16*   sw2b = (u16*)(ws + 9437184);        //  1 MB
    u16*   sw3b = (u16*)(ws + 10485760);       //  1 MB
    u16*   ew1b = (u16*)(ws + 11534336);       //  8 MB
    u16*   ew2b = (u16*)(ws + 19922944);       //  8 MB
    u16*   ew3b = (u16*)(ws + 28311552);       //  8 MB
    float* x12  = (float*)(ws + 36700160);     // 16 MB fp32 [x1|x2]; h12 aliases (12 MB)
    float* h12  = x12;
    u16*   sh   = (u16*)(ws + 53477376);       //  4 MB bf16; z aliases (3 MB)
    u16*   z    = sh;
    float* shw    = (float*)(ws + 57671680);
    float* expw   = shw + M_TOK;
    int*   top1   = (int*)(expw + M_TOK);
    int*   rowidx = top1 + M_TOK;
    int*   perm   = rowidx + M_TOK;
    int*   basep  = perm + MAXP;
    int*   cntp   = basep + 16;

    const int NSPLIT_NONE = 1 << 28;

    // one fused convert: 4587520 f4-groups == 17920 blocks exactly
    cvt_all_kernel<<<dim3(17920), dim3(256), 0, stream>>>(
        x, sw1, sw2, sw3, ew1, ew2, ew3,
        xb, sw1b, sw2b, sw3b, ew1b, ew2b, ew3b);

    gating_kernel<<<dim3(M_TOK), dim3(256), 0, stream>>>(x, index_b, index_t,
        sg_w, sg_b, eg_w, eg_b, exp_bias, shw, expw, top1, rowidx);
    bucket_kernel<<<dim3(1), dim3(256), 0, stream>>>(top1, basep, cntp, perm);

    // G1: xb @ [sw1;sw2]^T -> x12. 512 blocks.
    gemm_kernel<0, 1024><<<dim3(8, 64), dim3(256), 0, stream>>>(
        xb, D_DIM, sw1b, sw2b, H_DIM, sb1, sb2, x12,
        basep, cntp, perm, rowidx, shw, expw);
    // shared silu-gate + LN -> sh
    ln_kernel<false><<<dim3(BT_TOK), dim3(256), 0, stream>>>(
        x12, s_ln_g, s_ln_b, sh, basep, cntp);
    // G2: sh @ sw3^T -> d_out (all rows). 512 blocks.
    gemm_kernel<1, 512><<<dim3(8, 64), dim3(256), 0, stream>>>(
        sh, H_DIM, sw3b, sw3b, NSPLIT_NONE, sb3, sb3, out,
        basep, cntp, perm, rowidx, shw, expw);
    // E1: gathered xb @ [ew1;ew2][e]^T -> h12. <=384 blocks.
    gemm_kernel<2, 1024><<<dim3(8, MAXP / 64), dim3(256), 0, stream>>>(
        xb, D_DIM, ew1b, ew2b, H_DIM, eb1, eb2, h12,
        basep, cntp, perm, rowidx, shw, expw);
    // expert silu-gate + LN -> z (pad rows zeroed)
    ln_kernel<true><<<dim3(MAXP), dim3(256), 0, stream>>>(
        h12, sel_ln_g, sel_ln_b, z, basep, cntp);
    // E2: z @ ew3[e]^T, blend-scatter into d_out. <=384 blocks.
    gemm_kernel<3, 512><<<dim3(8, MAXP / 64), dim3(256), 0, stream>>>(
        z, H_DIM, ew3b, ew3b, NSPLIT_NONE, eb3, eb3, out,
        basep, cntp, perm, rowidx, shw, expw);
}